// Round 6
// baseline (258.239 us; speedup 1.0000x reference)
//
#include <hip/hip_runtime.h>
#include <hip/hip_fp16.h>
#include <math.h>

#define EPS_Q 1e-8f

struct F3 { float x, y, z; };
struct Q4 { F3 v; float w; };

typedef float    fvec4 __attribute__((ext_vector_type(4)));
typedef unsigned uvec4 __attribute__((ext_vector_type(4)));
typedef int      ivec2 __attribute__((ext_vector_type(2)));

__device__ __forceinline__ F3 add3(F3 a, F3 b){ return {a.x+b.x, a.y+b.y, a.z+b.z}; }
__device__ __forceinline__ F3 sub3(F3 a, F3 b){ return {a.x-b.x, a.y-b.y, a.z-b.z}; }
__device__ __forceinline__ F3 scal3(float s, F3 a){ return {s*a.x, s*a.y, s*a.z}; }
__device__ __forceinline__ float dot3(F3 a, F3 b){ return a.x*b.x + a.y*b.y + a.z*b.z; }
__device__ __forceinline__ F3 cross3(F3 a, F3 b){
    return { a.y*b.z - a.z*b.y, a.z*b.x - a.x*b.z, a.x*b.y - a.y*b.x };
}

__device__ __forceinline__ Q4 qmul(Q4 q, Q4 r){
    Q4 o;
    o.w = q.w*r.w - dot3(q.v, r.v);
    o.v = add3(add3(scal3(q.w, r.v), scal3(r.w, q.v)), cross3(q.v, r.v));
    return o;
}
__device__ __forceinline__ Q4 qconj(Q4 q){ return { {-q.v.x, -q.v.y, -q.v.z}, q.w }; }
__device__ __forceinline__ F3 qrot(Q4 q, F3 v){
    F3 t = scal3(2.0f, cross3(q.v, v));
    return add3(add3(v, scal3(q.w, t)), cross3(q.v, t));
}
// matches reference so3_log branch semantics exactly
__device__ __forceinline__ F3 so3_log(Q4 q){
    float n = sqrtf(dot3(q.v, q.v));
    float theta = 2.0f * atan2f(n, q.w);
    float k;
    if (n > EPS_Q) k = theta / n;
    else           k = 2.0f / ((fabsf(q.w) > EPS_Q) ? q.w : 1.0f);
    return scal3(k, q.v);
}

// non-temporal helpers for single-use streams
__device__ __forceinline__ float ntl (const float* p){ return __builtin_nontemporal_load(p); }
__device__ __forceinline__ void  nts (float* p, float v){ __builtin_nontemporal_store(v, p); }

__device__ __forceinline__ unsigned pack2h(float a, float b){
    __half2 h = __floats2half2_rn(a, b);
    unsigned u; __builtin_memcpy(&u, &h, 4);
    return u;
}
__device__ __forceinline__ float2 unp2h(unsigned u){
    __half2 h; __builtin_memcpy(&h, &u, 4);
    return __half22float2(h);
}

// ---------------------------------------------------------------------------
// pack kernel: nodes (28B f32 rows) -> nodes16 (16B fp16 rows).
// Vectorized LDS staging: all global reads are nt dwordx4 (R4's pack was
// scalar-staged and ran ~2 TB/s; this should stream at ~5-6 TB/s).
// ---------------------------------------------------------------------------
__global__ __launch_bounds__(256)
void pack_kernel(const float* __restrict__ nodes, uvec4* __restrict__ nodes16, int N)
{
    __shared__ __attribute__((aligned(16))) float s[7*256];
    const int tid   = threadIdx.x;
    const int base  = blockIdx.x * 256;
    const int nrows = min(256, N - base);
    const int ndw   = nrows * 7;
    const int nx4   = ndw >> 2;

    const float* src = nodes + 7*(size_t)base;   // 28*base bytes: 16B-aligned
    for (int idx = tid; idx < nx4; idx += 256) {
        fvec4 v = __builtin_nontemporal_load(reinterpret_cast<const fvec4*>(src) + idx);
        reinterpret_cast<fvec4*>(s)[idx] = v;
    }
    for (int idx = (nx4 << 2) + tid; idx < ndw; idx += 256)
        s[idx] = ntl(src + idx);
    __syncthreads();

    if (tid < nrows) {
        const float* r = s + 7*tid;   // stride 7 coprime with 32 banks: conflict-free
        uvec4 row = { pack2h(r[0], r[1]), pack2h(r[2], 0.0f),
                      pack2h(r[3], r[4]), pack2h(r[5], r[6]) };
        nodes16[base + tid] = row;    // cached store: keep L2/L3-resident for gathers
    }
}

// ---------------------------------------------------------------------------
// edge residual math
// ---------------------------------------------------------------------------
__device__ __forceinline__ void edge_math(F3 t1, Q4 q1, F3 t2, Q4 q2,
                                          F3 tp, Q4 qp, float res[6])
{
    Q4 qi1 = qconj(q1);
    F3 ti1 = scal3(-1.0f, qrot(qi1, t1));
    Q4 qa  = qmul(qi1, q2);
    F3 ta  = add3(ti1, qrot(qi1, t2));

    Q4 qip = qconj(qp);
    F3 tip = scal3(-1.0f, qrot(qip, tp));
    Q4 qe  = qmul(qip, qa);
    F3 te  = add3(tip, qrot(qip, ta));

    F3 phi = so3_log(qe);
    float theta2 = dot3(phi, phi);
    float theta  = sqrtf(theta2);
    float coef;
    if (theta < 1e-4f) {
        coef = 1.0f / 12.0f;
    } else {
        float s, c;
        sincosf(theta, &s, &c);
        coef = 1.0f / theta2 - (1.0f + c) / (2.0f * theta * s);
    }
    F3 pxt = cross3(phi, te);
    F3 tau = add3(sub3(te, scal3(0.5f, pxt)), scal3(coef, cross3(phi, pxt)));

    res[0] = tau.x; res[1] = tau.y; res[2] = tau.z;
    res[3] = phi.x; res[4] = phi.y; res[5] = phi.z;
}

// ---------------------------------------------------------------------------
// fused kernel: Bresenham-interleaved block roles (R2, proven) so streaming
// node blocks are co-resident with latency-bound edge blocks for the whole
// run.  Edge body = R5's edge_kernel3 verbatim (LDS-staged poses/out).
// ---------------------------------------------------------------------------
__global__ __launch_bounds__(256)
void fused_kernel(const int*   __restrict__ edges,
                  const uvec4* __restrict__ nodes16,
                  const float* __restrict__ poses,
                  const float* __restrict__ nodes,
                  const float* __restrict__ vels,
                  const float* __restrict__ imu_drots,
                  const float* __restrict__ imu_dtrans,
                  const float* __restrict__ imu_dvels,
                  const float* __restrict__ dts,
                  float*       __restrict__ out,
                  int E, int M, int NB, int T,
                  size_t off_adjvel, size_t off_imurot, size_t off_transvel)
{
    __shared__ __attribute__((aligned(16))) float sp[7*256];  // staged poses
    __shared__ __attribute__((aligned(16))) float so[6*256];  // staged outputs

    const int b   = blockIdx.x;
    const int tid = threadIdx.x;
    const long long f0 = ((long long)b       * NB) / T;
    const long long f1 = ((long long)(b + 1) * NB) / T;

    if (f1 > f0) {
        // ---------------- node-adjacency residuals (pure nt streaming) ----------------
        const int m = (int)f0 * 256 + tid;
        if (m >= M) return;

        const float* n0 = nodes + 7*(size_t)m;
        const float* n1 = nodes + 7*(size_t)(m+1);
        F3 t0 = {n0[0], n0[1], n0[2]};  Q4 q0 = {{n0[3], n0[4], n0[5]}, n0[6]};
        F3 t1 = {n1[0], n1[1], n1[2]};  Q4 q1 = {{n1[3], n1[4], n1[5]}, n1[6]};

        F3 v0 = {vels[3*(size_t)m],     vels[3*(size_t)m + 1], vels[3*(size_t)m + 2]};
        F3 v1 = {vels[3*(size_t)m + 3], vels[3*(size_t)m + 4], vels[3*(size_t)m + 5]};

        fvec4 drq = __builtin_nontemporal_load(reinterpret_cast<const fvec4*>(imu_drots) + m);
        Q4 dr = {{drq.x, drq.y, drq.z}, drq.w};

        F3 dvm = { ntl(imu_dvels + 3*(size_t)m),
                   ntl(imu_dvels + 3*(size_t)m + 1),
                   ntl(imu_dvels + 3*(size_t)m + 2) };
        F3 dtr = { ntl(imu_dtrans + 3*(size_t)m),
                   ntl(imu_dtrans + 3*(size_t)m + 1),
                   ntl(imu_dtrans + 3*(size_t)m + 2) };
        float dt = ntl(dts + m);

        F3 adjv = sub3(dvm, sub3(v1, v0));
        nts(out + off_adjvel + 3*(size_t)m,     0.1f * adjv.x);
        nts(out + off_adjvel + 3*(size_t)m + 1, 0.1f * adjv.y);
        nts(out + off_adjvel + 3*(size_t)m + 2, 0.1f * adjv.z);

        Q4 qre = qmul(qconj(dr), qmul(qconj(q0), q1));
        F3 rot = so3_log(qre);
        nts(out + off_imurot + 3*(size_t)m,     rot.x);
        nts(out + off_imurot + 3*(size_t)m + 1, rot.y);
        nts(out + off_imurot + 3*(size_t)m + 2, rot.z);

        F3 tv = sub3(sub3(t1, t0), add3(scal3(dt, v0), dtr));
        nts(out + off_transvel + 3*(size_t)m,     0.1f * tv.x);
        nts(out + off_transvel + 3*(size_t)m + 1, 0.1f * tv.y);
        nts(out + off_transvel + 3*(size_t)m + 2, 0.1f * tv.z);
    } else {
        // ---------------- edge residuals (R5 edge_kernel3 body) ----------------
        const int eb    = b - (int)f0;          // edge-block index
        const int b0    = eb * 256;             // first edge of this block
        const int nrows = min(256, E - b0);
        const bool active = (tid < nrows);

        // 1) long-latency gathers first
        ivec2 ij = {0, 0};
        uvec4 r1 = {0,0,0,0}, r2 = {0,0,0,0};
        if (active) {
            ij = __builtin_nontemporal_load(reinterpret_cast<const ivec2*>(edges) + (b0 + tid));
            r1 = nodes16[ij.x];
            r2 = nodes16[ij.y];
        }

        // 2) stage poses: coalesced nt dwordx4
        {
            const float* src = poses + 7*(size_t)b0;   // 16B-aligned (b0 % 4 == 0)
            const int ndw = nrows * 7;
            const int nx4 = ndw >> 2;
            for (int idx = tid; idx < nx4; idx += 256) {
                fvec4 v = __builtin_nontemporal_load(reinterpret_cast<const fvec4*>(src) + idx);
                reinterpret_cast<fvec4*>(sp)[idx] = v;
            }
            for (int idx = (nx4 << 2) + tid; idx < ndw; idx += 256)
                sp[idx] = ntl(src + idx);
        }
        __syncthreads();

        // 3) compute; results into LDS
        if (active) {
            const float* pr = sp + 7*tid;
            F3 tp = {pr[0], pr[1], pr[2]};
            Q4 qp = {{pr[3], pr[4], pr[5]}, pr[6]};

            float2 a0 = unp2h(r1.x), a1 = unp2h(r1.y), a2 = unp2h(r1.z), a3 = unp2h(r1.w);
            float2 c0 = unp2h(r2.x), c1 = unp2h(r2.y), c2 = unp2h(r2.z), c3 = unp2h(r2.w);
            F3 t1 = {a0.x, a0.y, a1.x};  Q4 q1 = {{a2.x, a2.y, a3.x}, a3.y};
            F3 t2 = {c0.x, c0.y, c1.x};  Q4 q2 = {{c2.x, c2.y, c3.x}, c3.y};

            float res[6];
            edge_math(t1, q1, t2, q2, tp, qp, res);
            #pragma unroll
            for (int k = 0; k < 6; ++k) so[6*tid + k] = res[k];
        }
        __syncthreads();

        // 4) coalesced full-line nt stores
        {
            float* dst = out + 6*(size_t)b0;           // 16B-aligned
            const int ndw = nrows * 6;
            const int nx4 = ndw >> 2;
            for (int idx = tid; idx < nx4; idx += 256) {
                fvec4 v = reinterpret_cast<const fvec4*>(so)[idx];
                __builtin_nontemporal_store(v, reinterpret_cast<fvec4*>(dst) + idx);
            }
            for (int idx = (nx4 << 2) + tid; idx < ndw; idx += 256)
                nts(dst + idx, so[idx]);
        }
    }
}

// ---------------------------------------------------------------------------
// fallback path (workspace too small): direct f32 gathers + separate node kernel
// ---------------------------------------------------------------------------
__global__ __launch_bounds__(256)
void edge_kernel_direct(const int*   __restrict__ edges,
                        const float* __restrict__ nodes,
                        const float* __restrict__ poses,
                        float*       __restrict__ out,
                        int E)
{
    const int e = blockIdx.x * 256 + threadIdx.x;
    if (e >= E) return;

    ivec2 ij = __builtin_nontemporal_load(reinterpret_cast<const ivec2*>(edges) + e);
    const float* n1 = nodes + 7*(size_t)ij.x;
    const float* n2 = nodes + 7*(size_t)ij.y;
    const float* p  = poses + 7*(size_t)e;

    F3 t1 = {n1[0], n1[1], n1[2]};  Q4 q1 = {{n1[3], n1[4], n1[5]}, n1[6]};
    F3 t2 = {n2[0], n2[1], n2[2]};  Q4 q2 = {{n2[3], n2[4], n2[5]}, n2[6]};

    float res[6];
    edge_math(t1, q1, t2, q2,
              F3{ntl(p+0), ntl(p+1), ntl(p+2)}, Q4{{ntl(p+3), ntl(p+4), ntl(p+5)}, ntl(p+6)},
              res);
    float* o = out + 6*(size_t)e;
    #pragma unroll
    for (int k = 0; k < 6; ++k) nts(o + k, res[k]);
}

__global__ __launch_bounds__(256)
void node_kernel(const float* __restrict__ nodes,
                 const float* __restrict__ vels,
                 const float* __restrict__ imu_drots,
                 const float* __restrict__ imu_dtrans,
                 const float* __restrict__ imu_dvels,
                 const float* __restrict__ dts,
                 float*       __restrict__ out,
                 int M,
                 size_t off_adjvel, size_t off_imurot, size_t off_transvel)
{
    const int m = blockIdx.x * 256 + threadIdx.x;
    if (m >= M) return;

    const float* n0 = nodes + 7*(size_t)m;
    const float* n1 = nodes + 7*(size_t)(m+1);
    F3 t0 = {n0[0], n0[1], n0[2]};  Q4 q0 = {{n0[3], n0[4], n0[5]}, n0[6]};
    F3 t1 = {n1[0], n1[1], n1[2]};  Q4 q1 = {{n1[3], n1[4], n1[5]}, n1[6]};

    F3 v0 = {vels[3*(size_t)m],     vels[3*(size_t)m + 1], vels[3*(size_t)m + 2]};
    F3 v1 = {vels[3*(size_t)m + 3], vels[3*(size_t)m + 4], vels[3*(size_t)m + 5]};

    fvec4 drq = __builtin_nontemporal_load(reinterpret_cast<const fvec4*>(imu_drots) + m);
    Q4 dr = {{drq.x, drq.y, drq.z}, drq.w};

    F3 dvm = { ntl(imu_dvels + 3*(size_t)m),
               ntl(imu_dvels + 3*(size_t)m + 1),
               ntl(imu_dvels + 3*(size_t)m + 2) };
    F3 dtr = { ntl(imu_dtrans + 3*(size_t)m),
               ntl(imu_dtrans + 3*(size_t)m + 1),
               ntl(imu_dtrans + 3*(size_t)m + 2) };
    float dt = ntl(dts + m);

    F3 adjv = sub3(dvm, sub3(v1, v0));
    nts(out + off_adjvel + 3*(size_t)m,     0.1f * adjv.x);
    nts(out + off_adjvel + 3*(size_t)m + 1, 0.1f * adjv.y);
    nts(out + off_adjvel + 3*(size_t)m + 2, 0.1f * adjv.z);

    Q4 qre = qmul(qconj(dr), qmul(qconj(q0), q1));
    F3 rot = so3_log(qre);
    nts(out + off_imurot + 3*(size_t)m,     rot.x);
    nts(out + off_imurot + 3*(size_t)m + 1, rot.y);
    nts(out + off_imurot + 3*(size_t)m + 2, rot.z);

    F3 tv = sub3(sub3(t1, t0), add3(scal3(dt, v0), dtr));
    nts(out + off_transvel + 3*(size_t)m,     0.1f * tv.x);
    nts(out + off_transvel + 3*(size_t)m + 1, 0.1f * tv.y);
    nts(out + off_transvel + 3*(size_t)m + 2, 0.1f * tv.z);
}

extern "C" void kernel_launch(void* const* d_in, const int* in_sizes, int n_in,
                              void* d_out, int out_size, void* d_ws, size_t ws_size,
                              hipStream_t stream) {
    const int*   edges      = (const int*)  d_in[0];
    const float* nodes      = (const float*)d_in[1];
    const float* vels       = (const float*)d_in[2];
    const float* poses      = (const float*)d_in[3];
    const float* imu_drots  = (const float*)d_in[4];
    const float* imu_dtrans = (const float*)d_in[5];
    const float* imu_dvels  = (const float*)d_in[6];
    const float* dts        = (const float*)d_in[7];
    float* out = (float*)d_out;

    const int E = in_sizes[0] / 2;
    const int N = in_sizes[1] / 7;
    const int M = in_sizes[7];

    const size_t off_adjvel   = 6*(size_t)E;
    const size_t off_imurot   = off_adjvel + 3*(size_t)M;
    const size_t off_transvel = off_imurot + 3*(size_t)M;

    const int BLK = 256;
    const int EB = (E + BLK - 1) / BLK;
    const int NB = (M + BLK - 1) / BLK;
    const int T  = EB + NB;

    uvec4* nodes16 = (uvec4*)d_ws;
    const bool can_pack = (d_ws != nullptr) && (ws_size >= (size_t)N * 16);

    if (can_pack) {
        pack_kernel<<<(N + BLK - 1)/BLK, BLK, 0, stream>>>(nodes, nodes16, N);
        fused_kernel<<<T, BLK, 0, stream>>>(edges, nodes16, poses,
                                            nodes, vels, imu_drots, imu_dtrans,
                                            imu_dvels, dts, out, E, M, NB, T,
                                            off_adjvel, off_imurot, off_transvel);
    } else {
        edge_kernel_direct<<<EB, BLK, 0, stream>>>(edges, nodes, poses, out, E);
        node_kernel<<<NB, BLK, 0, stream>>>(nodes, vels, imu_drots, imu_dtrans,
                                            imu_dvels, dts, out, M,
                                            off_adjvel, off_imurot, off_transvel);
    }
}